// Round 2
// baseline (254.418 us; speedup 1.0000x reference)
//
#include <hip/hip_runtime.h>

typedef __bf16 bf16;
typedef __attribute__((ext_vector_type(4))) __bf16 bf16x4;
typedef __attribute__((ext_vector_type(8))) __bf16 bf16x8;
typedef __attribute__((ext_vector_type(4))) float f32x4;
typedef __attribute__((ext_vector_type(16))) float f32x16;

#define MFMA16(a, b, c) __builtin_amdgcn_mfma_f32_16x16x32_bf16((a), (b), (c), 0, 0, 0)
#define MFMA32(a, b, c) __builtin_amdgcn_mfma_f32_32x32x16_bf16((a), (b), (c), 0, 0, 0)

// RNE fp32->bf16 (epilogue)
__device__ __forceinline__ bf16 tobf(float f) {
    unsigned u = __float_as_uint(f);
    u += 0x7fffu + ((u >> 16) & 1u);
    unsigned short h = (unsigned short)(u >> 16);
    bf16 r;
    __builtin_memcpy(&r, &h, 2);
    return r;
}

// async global->LDS, 16B per lane. Side-effecting: the compiler cannot sink it.
__device__ __forceinline__ void stage16(const void* g, void* l) {
    __builtin_amdgcn_global_load_lds(
        (const __attribute__((address_space(1))) unsigned int*)g,
        (__attribute__((address_space(3))) unsigned int*)l, 16, 0, 0);
}

// ---------------------------------------------------------------------------
// W [1024][64] fp32 -> Wt [3][64][1024] bf16 (transposed)
// ---------------------------------------------------------------------------
__global__ void wconv_kernel(const float* __restrict__ Wq, const float* __restrict__ Wk,
                             const float* __restrict__ Wv, bf16* __restrict__ Wt) {
    int j = blockIdx.y;
    const float* W = (j == 0) ? Wq : ((j == 1) ? Wk : Wv);
    int idx = blockIdx.x * 256 + threadIdx.x;
    int m = idx >> 6, n = idx & 63;
    Wt[(size_t)j * 65536 + (size_t)n * 1024 + m] = tobf(W[idx]);
}

// ---------------------------------------------------------------------------
// Projections v7: A staged via global_load_lds width-16 (DMA, zero VGPRs, the
// compiler cannot sink it -> the prefetch provably stays in flight across the
// compute phase). BK=64 fp32 tile (16 KB), double-buffered = 32 KB LDS -> all
// 768 blocks co-resident at 3/CU. A-tile is XOR-swizzled (r ^= (row&7)<<4)
// via PRE-SWIZZLED GLOBAL SOURCE (linear LDS dest, rule: both-sides-or-
// neither) so per-row b128 fragment reads are bank-conflict-free.
// B (W tile) never touches LDS: per-wave bf16 fragment loads straight from
// Wt, L1/L2-resident (16 KB working set shared by all blocks of same j).
// Per tile: STAGE(next) -> B loads -> LDS-read A + cvt + MFMA -> syncthreads.
// Stage ops are issued BEFORE the B loads, so the MFMA's vmcnt wait for B
// leaves the stage in flight; the barrier drain is covered by compute.
// ---------------------------------------------------------------------------
__launch_bounds__(256, 3)
__global__ void proj_kernel(const float* __restrict__ Q, const float* __restrict__ K,
                            const float* __restrict__ V, const bf16* __restrict__ Wt,
                            const float* __restrict__ bq, const float* __restrict__ bk,
                            const float* __restrict__ bv,
                            bf16* __restrict__ q_ws, bf16* __restrict__ k_ws,
                            bf16* __restrict__ vT_ws) {
    const int j = blockIdx.y;
    const float* In   = (j == 0) ? Q : ((j == 1) ? K : V);
    const float* bias = (j == 0) ? bq : ((j == 1) ? bk : bv);
    const bf16* W = Wt + (size_t)j * 65536;

    __shared__ float As[2][64][64];   // 32 KB: [buf][row][k], rows XOR-swizzled

    const int tid = threadIdx.x;
    const int wave = tid >> 6, lane = tid & 63;
    const int quad = lane >> 4, l16 = lane & 15;
    const int rbase = blockIdx.x * 64;

    // --- staging maps (4 insts of 16B x 256 thr = 16 KB tile) --------------
    // linear LDS byte x = u*16, u = i*256+tid; row = u>>4, granule = u&15.
    // source granule is inverse-swizzled: r_g = (granule*16) ^ ((row&7)<<4).
    const char* asrc[4];
    char* adst0[4];
    char* adst1[4];
#pragma unroll
    for (int i = 0; i < 4; i++) {
        int u = i * 256 + tid;
        int row = u >> 4;
        int rg = ((u & 15) * 16) ^ ((row & 7) << 4);
        asrc[i] = (const char*)(In + (size_t)(rbase + row) * 1024) + rg;
        adst0[i] = (char*)&As[0][0][0] + u * 16;
        adst1[i] = (char*)&As[1][0][0] + u * 16;
    }

    // prologue: stage tile 0 into buf 0
#pragma unroll
    for (int i = 0; i < 4; i++) stage16(asrc[i], adst0[i]);
    __syncthreads();

    f32x4 acc[4];
#pragma unroll
    for (int nt = 0; nt < 4; nt++) acc[nt] = {0.f, 0.f, 0.f, 0.f};

    const int row = wave * 16 + l16;              // A-fragment row (0..63)
    const char* arow = (const char*)&As[0][row][0];
    const int sw = (l16 & 7) << 4;
    const bf16* wrow = W + quad * 8;              // + (nt*16+l16)*1024 + k

#pragma unroll 2
    for (int t = 0; t < 16; ++t) {
        const int cur = t & 1;
        // stage next tile (stays in flight across everything below)
        if (t < 15) {
#pragma unroll
            for (int i = 0; i < 4; i++)
                stage16(asrc[i] + (t + 1) * 256, cur ? adst0[i] : adst1[i]);
        }
        // B fragments for this tile straight from global (L1/L2-resident).
        // Issued AFTER the stage ops -> waiting on these does not drain stage.
        bf16x8 bf[2][4];
#pragma unroll
        for (int c = 0; c < 2; c++)
#pragma unroll
            for (int nt = 0; nt < 4; nt++)
                bf[c][nt] = *(const bf16x8*)(wrow + (size_t)(nt * 16 + l16) * 1024 +
                                             t * 64 + c * 32);
        // A fragments from LDS (swizzled read), cvt fp32->bf16, MFMA
        const char* ab = arow + (size_t)cur * 16384;
#pragma unroll
        for (int c = 0; c < 2; c++) {
            f32x4 a0 = *(const f32x4*)(ab + ((c * 128 + quad * 32) ^ sw));
            f32x4 a1 = *(const f32x4*)(ab + ((c * 128 + quad * 32 + 16) ^ sw));
            bf16x8 av;
            av[0] = (bf16)a0[0]; av[1] = (bf16)a0[1];
            av[2] = (bf16)a0[2]; av[3] = (bf16)a0[3];
            av[4] = (bf16)a1[0]; av[5] = (bf16)a1[1];
            av[6] = (bf16)a1[2]; av[7] = (bf16)a1[3];
#pragma unroll
            for (int nt = 0; nt < 4; nt++) acc[nt] = MFMA16(av, bf[c][nt], acc[nt]);
        }
        __syncthreads();   // stage(t+1) complete; buf safe to flip
    }

    const float scale = (j == 0) ? 0.125f * 1.44269504088896f : 1.0f;

    if (j != 2) {
        bf16* dst = (j == 0) ? q_ws : k_ws;
#pragma unroll
        for (int nt = 0; nt < 4; nt++) {
            int n = nt * 16 + l16;
            float bb = bias[n];
#pragma unroll
            for (int r4 = 0; r4 < 4; r4++) {
                int orow = rbase + wave * 16 + quad * 4 + r4;
                dst[(size_t)orow * 64 + n] = tobf((acc[nt][r4] + bb) * scale);
            }
        }
    } else {
        // v: transpose via LDS. vtile (9216 B) sits inside As[0] (16384 B);
        // the final tile (t=15) was read from As[1] -> disjoint, no barrier
        // needed before the writes.
        bf16 (*vtile)[72] = (bf16(*)[72])As;
#pragma unroll
        for (int nt = 0; nt < 4; nt++) {
            int n = nt * 16 + l16;
            float bb = bias[n];
#pragma unroll
            for (int r4 = 0; r4 < 4; r4++) {
                vtile[n][wave * 16 + quad * 4 + r4] = tobf(acc[nt][r4] + bb);
            }
        }
        __syncthreads();
        int bi = rbase >> 12, t0 = rbase & 4095;
        int d = tid >> 2, part = (tid & 3) * 16;
        bf16x8 x0 = *(const bf16x8*)&vtile[d][part];
        bf16x8 x1 = *(const bf16x8*)&vtile[d][part + 8];
        bf16* dst = vT_ws + (size_t)(bi * 64 + d) * 4096 + t0 + part;
        *(bf16x8*)dst = x0;
        *(bf16x8*)(dst + 8) = x1;
    }
}

// ---------------------------------------------------------------------------
// Flash attention v3 (unchanged): no-max softmax, S^T trick, K-split.
// ---------------------------------------------------------------------------
__launch_bounds__(256, 4)
__global__ void attn_kernel(const bf16* __restrict__ q_ws, const bf16* __restrict__ k_ws,
                            const bf16* __restrict__ vT_ws,
                            float* __restrict__ po, float* __restrict__ pl,
                            float* __restrict__ out, int keys_per_split, int direct) {
    const int b = blockIdx.z, split = blockIdx.y;
    const int tid = threadIdx.x, wave = tid >> 6, lane = tid & 63;
    const int l32 = lane & 31, h = lane >> 5;
    const int sw = l32 & 7;

    __shared__ bf16 kt[64][64];
    __shared__ bf16 vt[64][64];
    __shared__ bf16 pt[4][32][64];

    const int qrow0 = b * 4096 + blockIdx.x * 128 + wave * 32;

    bf16x8 qf[4];
    const bf16* qp = q_ws + (size_t)(qrow0 + l32) * 64 + h * 8;
#pragma unroll
    for (int c = 0; c < 4; c++) qf[c] = *(const bf16x8*)(qp + c * 16);

    f32x16 o0, o1;
    float l_lane = 0.f;
#pragma unroll
    for (int i = 0; i < 16; i++) { o0[i] = 0.f; o1[i] = 0.f; }

    const int key0 = split * keys_per_split;
    const int srow = tid >> 3;
    const int sg = tid & 7;
    const int sgk = sg ^ (srow & 7);
    const bf16* kg = k_ws + (size_t)(b * 4096 + key0 + srow) * 64 + sg * 8;
    const bf16* vg = vT_ws + (size_t)(b * 64 + srow) * 4096 + key0 + sg * 8;

    uint4 kv0 = *(const uint4*)kg;
    uint4 kv1 = *(const uint4*)(kg + 2048);
    uint4 vv0 = *(const uint4*)vg;
    uint4 vv1 = *(const uint4*)(vg + 131072);

    for (int t0 = 0; t0 < keys_per_split; t0 += 64) {
        __syncthreads();
        *(uint4*)&kt[srow][sgk * 8]      = kv0;
        *(uint4*)&kt[srow + 32][sgk * 8] = kv1;
        *(uint4*)&vt[srow][sgk * 8]      = vv0;
        *(uint4*)&vt[srow + 32][sgk * 8] = vv1;
        if (t0 + 64 < keys_per_split) {
            kv0 = *(const uint4*)(kg + (size_t)(t0 + 64) * 64);
            kv1 = *(const uint4*)(kg + (size_t)(t0 + 64) * 64 + 2048);
            vv0 = *(const uint4*)(vg + t0 + 64);
            vv1 = *(const uint4*)(vg + t0 + 64 + 131072);
        }
        __syncthreads();

#pragma unroll
        for (int kt32 = 0; kt32 < 2; kt32++) {
            f32x16 s;
#pragma unroll
            for (int i = 0; i < 16; i++) s[i] = 0.f;
#pragma unroll
            for (int c = 0; c < 4; c++) {
                bf16x8 kf = *(const bf16x8*)(&kt[kt32 * 32 + l32][((2 * c + h) ^ sw) * 8]);
                s = MFMA32(kf, qf[c], s);
            }
#pragma unroll
            for (int g = 0; g < 4; g++) {
                float p0 = __builtin_amdgcn_exp2f(s[4 * g + 0]);
                float p1 = __builtin_amdgcn_exp2f(s[4 * g + 1]);
                float p2 = __builtin_amdgcn_exp2f(s[4 * g + 2]);
                float p3 = __builtin_amdgcn_exp2f(s[4 * g + 3]);
                l_lane += (p0 + p1) + (p2 + p3);
                bf16x4 pk;
                pk[0] = (bf16)p0; pk[1] = (bf16)p1; pk[2] = (bf16)p2; pk[3] = (bf16)p3;
                int gp = (kt32 * 4 + g) ^ sw;
                *(bf16x4*)(&pt[wave][l32][gp * 8 + 4 * h]) = pk;
            }
        }

#pragma unroll
        for (int tc = 0; tc < 4; tc++) {
            int gp = ((2 * tc + h) ^ sw) * 8;
            bf16x8 pf  = *(const bf16x8*)(&pt[wave][l32][gp]);
            bf16x8 vf0 = *(const bf16x8*)(&vt[l32][gp]);
            bf16x8 vf1 = *(const bf16x8*)(&vt[32 + l32][gp]);
            o0 = MFMA32(pf, vf0, o0);
            o1 = MFMA32(pf, vf1, o1);
        }
    }

    l_lane += __shfl_xor(l_lane, 32);

    if (direct) {
        float* orow = out + (size_t)qrow0 * 64;
#pragma unroll
        for (int i = 0; i < 16; i++) {
            int R = (i & 3) + 8 * (i >> 2) + 4 * h;
            float inv = 1.0f / __shfl(l_lane, R);
            orow[(size_t)R * 64 + l32]      = o0[i] * inv;
            orow[(size_t)R * 64 + 32 + l32] = o1[i] * inv;
        }
    } else {
        size_t prow = (size_t)split * 16384 + qrow0;
        float* pob = po + prow * 64;
#pragma unroll
        for (int i = 0; i < 16; i++) {
            int R = (i & 3) + 8 * (i >> 2) + 4 * h;
            pob[(size_t)R * 64 + l32]      = o0[i];
            pob[(size_t)R * 64 + 32 + l32] = o1[i];
        }
        if (h == 0) pl[prow + l32] = l_lane;
    }
}

// ---------------------------------------------------------------------------
// Combine K-split partials: out = sum(po) / sum(pl)
// ---------------------------------------------------------------------------
__launch_bounds__(256)
__global__ void combine_kernel(const float* __restrict__ po, const float* __restrict__ pl,
                               float* __restrict__ out, int nsplit) {
    int idx = blockIdx.x * 256 + threadIdx.x;
    int row = idx >> 6;
    float so = 0.f, sl = 0.f;
    for (int s = 0; s < nsplit; s++) {
        so += po[(size_t)s * 1048576 + idx];
        sl += pl[(size_t)s * 16384 + row];
    }
    out[idx] = so / sl;
}

// ---------------------------------------------------------------------------
extern "C" void kernel_launch(void* const* d_in, const int* in_sizes, int n_in,
                              void* d_out, int out_size, void* d_ws, size_t ws_size,
                              hipStream_t stream) {
    const float* Q  = (const float*)d_in[0];
    const float* K  = (const float*)d_in[1];
    const float* V  = (const float*)d_in[2];
    const float* Wq = (const float*)d_in[3];
    const float* bq = (const float*)d_in[4];
    const float* Wk = (const float*)d_in[5];
    const float* bk = (const float*)d_in[6];
    const float* Wv = (const float*)d_in[7];
    const float* bv = (const float*)d_in[8];
    float* out = (float*)d_out;

    char* ws = (char*)d_ws;
    bf16* Wt    = (bf16*)ws;                              // 384 KB
    bf16* q_ws  = (bf16*)(ws + 393216);                   // 2 MB
    bf16* k_ws  = (bf16*)(ws + 393216 + 2097152);         // 2 MB
    bf16* vT_ws = (bf16*)(ws + 393216 + 2 * 2097152);     // 2 MB
    const size_t base = 393216 + 3 * 2097152;

    const size_t per_split = 16384u * 4u + 1048576u * 4u;
    int nsplit = 1;
    if (ws_size >= base + 8 * per_split) nsplit = 8;
    else if (ws_size >= base + 4 * per_split) nsplit = 4;
    else if (ws_size >= base + 2 * per_split) nsplit = 2;

    float* pl = (float*)(ws + base);
    float* po = (float*)(ws + base + (size_t)nsplit * 65536);

    hipLaunchKernelGGL(wconv_kernel, dim3(256, 3), dim3(256), 0, stream, Wq, Wk, Wv, Wt);
    hipLaunchKernelGGL(proj_kernel, dim3(256, 3), dim3(256), 0, stream,
                       Q, K, V, Wt, bq, bk, bv, q_ws, k_ws, vT_ws);
    hipLaunchKernelGGL(attn_kernel, dim3(32, nsplit, 4), dim3(256), 0, stream,
                       q_ws, k_ws, vT_ws, po, pl, out, 4096 / nsplit, nsplit == 1 ? 1 : 0);
    if (nsplit > 1) {
        hipLaunchKernelGGL(combine_kernel, dim3(4096), dim3(256), 0, stream, po, pl, out, nsplit);
    }
}